// Round 13
// baseline (288.522 us; speedup 1.0000x reference)
//
#include <hip/hip_runtime.h>

#define B_SZ 4096
#define S_SZ 128
#define XD 5
#define EH 128
#define DH 256
#define DSTEPS 10

typedef short v8s __attribute__((ext_vector_type(8)));
typedef float v4f __attribute__((ext_vector_type(4)));

__device__ __forceinline__ float bf2f(unsigned short u) {
    union { unsigned int i; float f; } v; v.i = ((unsigned int)u) << 16; return v.f;
}
__device__ __forceinline__ unsigned short f2bf(float f) {
    union { float f; unsigned int i; } v; v.f = f;
    unsigned int x = v.i;
    return (unsigned short)((x + 0x7FFFu + ((x >> 16) & 1u)) >> 16);
}
__device__ __forceinline__ float fexp2(float x) { return __builtin_amdgcn_exp2f(x); }
__device__ __forceinline__ float frcp(float x) { return __builtin_amdgcn_rcpf(x); }
// pack 2 f32 -> 1 u32 of 2 bf16 (low word = first operand). HW-verified.
__device__ __forceinline__ unsigned int cvt2bf(float lo, float hi) {
    unsigned int r;
    asm("v_cvt_pk_bf16_f32 %0, %1, %2" : "=v"(r) : "v"(lo), "v"(hi));
    return r;
}

#define SC_S (-1.44269504088896f)   // sigmoid: rcp(1+exp2(SC_S*x))
#define SC_T ( 2.88539008177793f)   // tanh:    1-2*rcp(exp2(SC_T*x)+1)

// ---------------------------------------------------------------- encoder v4
// UNCHANGED from the measured-good R6/R8 version (104.5 us incl. the
// decoder weight-conversion side-job).
__global__ __launch_bounds__(512) void enc_kernel(
    const float* __restrict__ x,       // [B][S][5] fp32
    const float* __restrict__ Wih32,   // [384][5] fp32
    const float* __restrict__ Whh32,   // [384][128] fp32
    const float* __restrict__ bih,     // [384] fp32
    const float* __restrict__ bhh,     // [384] fp32
    const float* __restrict__ dWih,    // [768][129] fp32
    const float* __restrict__ dWhh,    // [768][256] fp32
    unsigned short* __restrict__ wihp,     // out: [768][136] bf16 (col128=y wt), SCALED
    unsigned short* __restrict__ dWhh_bf,  // out: [768][256] bf16, SCALED
    unsigned short* __restrict__ ctex)     // out: [B][128] bf16
{
    __shared__ unsigned short xs[S_SZ][16][8];     // 32 KB (slot5 = 1.0)
    __shared__ unsigned short hb[2][16][136];      // 8.5 KB, +8 pad
    __shared__ __align__(16) unsigned short zpad[8];

    const int tid = threadIdx.x;
    const int bid = blockIdx.x;
    const int wv = tid >> 6;
    const int lane = tid & 63;
    const int n = lane & 15;
    const int kg = lane >> 4;       // K-group / C-row quad
    const int r0 = bid * 16;

    // side-job: decoder weight conversion WITH activation scales folded in.
    for (int i = bid * 512 + tid; i < 768 * 256; i += 131072) {
        const float sc = ((i >> 8) < 512) ? SC_S : SC_T;
        dWhh_bf[i] = f2bf(sc * dWhh[i]);
    }
    for (int i = bid * 512 + tid; i < 768 * 136; i += 131072) {
        int col = i / 136, k = i - col * 136;
        const float sc = (col < 512) ? SC_S : SC_T;
        wihp[i] = (k < 129) ? f2bf(sc * dWih[col * 129 + k]) : (unsigned short)0;
    }

    for (int i = tid; i < 2 * 16 * 136; i += 512) ((unsigned short*)hb)[i] = 0;
    if (tid < 8) zpad[tid] = 0;
    for (int i = tid; i < 16 * S_SZ * 8; i += 512) {
        int m = i >> 10;
        int rem = i & 1023;
        int t = rem >> 3;
        int j = rem & 7;
        unsigned short v = 0;
        if (j < XD) v = f2bf(x[(size_t)(r0 + m) * (S_SZ * XD) + t * XD + j]);
        else if (j == XD) v = 0x3F80;          // constant-1 bias carrier
        xs[t][m][j] = v;
    }

    const int colw = wv * 16 + n;
    v8s fw[3][4];
    v8s fx[3];
    #pragma unroll
    for (int g = 0; g < 3; ++g) {
        const float sc = (g < 2) ? SC_S : SC_T;
        const int gcol = g * EH + colw;
        #pragma unroll
        for (int kt = 0; kt < 4; ++kt) {
            const float* p = &Whh32[(size_t)gcol * EH + kt * 32 + kg * 8];
            float4 lo = *(const float4*)p;
            float4 hi = *(const float4*)(p + 4);
            v8s f;
            f[0] = (short)f2bf(sc * lo.x); f[1] = (short)f2bf(sc * lo.y);
            f[2] = (short)f2bf(sc * lo.z); f[3] = (short)f2bf(sc * lo.w);
            f[4] = (short)f2bf(sc * hi.x); f[5] = (short)f2bf(sc * hi.y);
            f[6] = (short)f2bf(sc * hi.z); f[7] = (short)f2bf(sc * hi.w);
            fw[g][kt] = f;
        }
        v8s t = {0, 0, 0, 0, 0, 0, 0, 0};
        if (kg == 0) {
            const float* p = &Wih32[gcol * XD];
            #pragma unroll
            for (int j = 0; j < XD; ++j) t[j] = (short)f2bf(sc * p[j]);
            float b = (g < 2) ? (sc * (bih[gcol] + bhh[gcol]))
                              : (sc * bih[gcol]);
            t[XD] = (short)f2bf(b);
        }
        fx[g] = t;
    }
    const float bhn = SC_T * bhh[2 * EH + colw];

    const v4f vzero = {0.f, 0.f, 0.f, 0.f};
    float hst[4] = {0.f, 0.f, 0.f, 0.f};
    __syncthreads();

    #pragma unroll 2
    for (int t = 0; t < S_SZ; ++t) {
        const int p = t & 1;
        v8s a[4];
        #pragma unroll
        for (int kt = 0; kt < 4; ++kt)
            a[kt] = *(const v8s*)&hb[p][n][kt * 32 + kg * 8];
        const unsigned short* xsrc = (kg == 0) ? &xs[t][n][0] : &zpad[0];
        v8s ax = *(const v8s*)xsrc;

        v4f accr  = __builtin_amdgcn_mfma_f32_16x16x32_bf16(a[0], fw[0][0], vzero, 0, 0, 0);
        v4f accz  = __builtin_amdgcn_mfma_f32_16x16x32_bf16(a[0], fw[1][0], vzero, 0, 0, 0);
        v4f acchn = __builtin_amdgcn_mfma_f32_16x16x32_bf16(a[0], fw[2][0], vzero, 0, 0, 0);
        #pragma unroll
        for (int kt = 1; kt < 4; ++kt) {
            accr  = __builtin_amdgcn_mfma_f32_16x16x32_bf16(a[kt], fw[0][kt], accr, 0, 0, 0);
            accz  = __builtin_amdgcn_mfma_f32_16x16x32_bf16(a[kt], fw[1][kt], accz, 0, 0, 0);
            acchn = __builtin_amdgcn_mfma_f32_16x16x32_bf16(a[kt], fw[2][kt], acchn, 0, 0, 0);
        }
        accr = __builtin_amdgcn_mfma_f32_16x16x32_bf16(ax, fx[0], accr, 0, 0, 0);
        accz = __builtin_amdgcn_mfma_f32_16x16x32_bf16(ax, fx[1], accz, 0, 0, 0);
        v4f accin = __builtin_amdgcn_mfma_f32_16x16x32_bf16(ax, fx[2], vzero, 0, 0, 0);

        float hnew[4];
        #pragma unroll
        for (int e = 0; e < 4; ++e) {
            float r  = frcp(1.f + fexp2(accr[e]));
            float z  = frcp(1.f + fexp2(accz[e]));
            float nn = 1.f - 2.f * frcp(fexp2(accin[e] + r * (acchn[e] + bhn)) + 1.f);
            float h  = nn + z * (hst[e] - nn);
            hst[e] = h;
            hnew[e] = h;
        }
        const unsigned int pk01 = cvt2bf(hnew[0], hnew[1]);
        const unsigned int pk23 = cvt2bf(hnew[2], hnew[3]);
        hb[1 - p][kg * 4 + 0][colw] = (unsigned short)(pk01 & 0xFFFFu);
        hb[1 - p][kg * 4 + 1][colw] = (unsigned short)(pk01 >> 16);
        hb[1 - p][kg * 4 + 2][colw] = (unsigned short)(pk23 & 0xFFFFu);
        hb[1 - p][kg * 4 + 3][colw] = (unsigned short)(pk23 >> 16);
        __syncthreads();
    }
    #pragma unroll
    for (int e = 0; e < 4; ++e)
        ctex[(size_t)(r0 + kg * 4 + e) * EH + colw] = f2bf(hst[e]);
}

// ---------------------------------------------------------------- fused decoder v6
// R8's v5 (verified PASS) with the weight-residency DELETED. Lesson from
// R7/R9/R12: the allocator will NOT hold ~100 VGPRs of weights (128/64-reg
// caps -> spill/remat every time). R10's accidental remat showed streaming
// B-frags from L2 per step runs the dec phase at ~40us (393KB/block/step,
// 1GB L2 aggregate ~29us floor). So: stream the 6 (gate,cg) B-frags per
// K-tile straight from the pre-converted bf16 workspace inside the step
// loop. An empty-asm barrier on the weight base per t-iteration defeats
// LICM re-hoisting (which would recreate the 192-reg spill).
// Register footprint ~90 < 128 cap -> no spill.
__global__ __launch_bounds__(512, 2)
void dec_all_kernel(
    const unsigned short* __restrict__ dWhh_bf, // [768][256] bf16, SCALED
    const unsigned short* __restrict__ wihp,    // [768][136] bf16, SCALED
    const float* __restrict__ dbih,   // [768]
    const float* __restrict__ dbhh,   // [768]
    const float* __restrict__ y,      // [B][128] fp32
    const unsigned short* __restrict__ ctex,  // [B][128] bf16
    const float* __restrict__ linW,   // [4][256] fp32
    const float* __restrict__ linb,   // [4] fp32
    float* __restrict__ out)          // [B][S][4] fp32
{
    __shared__ unsigned short hshf[32 * 16 * 8];   // 8 KB  h state (frag)
    __shared__ unsigned short lwf[32 * 16 * 8];    // 8 KB  linW (frag, 4->16 pad)
    __shared__ float gish[512 * 29];               // 58 KB gi[3][2] (24f) + bN[cg0] (4f)
    __shared__ float wysh[512 * 29];               // 58 KB wy[3][2] (24f) + bN[cg1] (4f)
    __shared__ float ysh[16][DSTEPS];              // 640 B y slab

    const int tid  = threadIdx.x;
    const int w    = tid >> 6;
    const int lane = tid & 63;
    const int n    = lane & 15;
    const int kg   = lane >> 4;
    const int rb   = blockIdx.x * 16;
    const int cbase = w * 32;

    // stage linW into frag layout
    {
        int col = tid >> 5, kgrp = tid & 31;
        unsigned short v8[8];
        #pragma unroll
        for (int j = 0; j < 8; ++j)
            v8[j] = (col < 4) ? f2bf(linW[col * 256 + kgrp * 8 + j]) : (unsigned short)0;
        *(uint4*)&lwf[(kgrp * 16 + col) * 8] = *(uint4*)v8;
    }
    // stage y slab: 16 rows x 10 steps
    if (tid < 16 * DSTEPS) {
        int row = tid / DSTEPS, tt = tid - row * DSTEPS;
        ysh[row][tt] = y[(size_t)(rb + row) * S_SZ + tt];
    }
    // h0 = 1
    for (int i = tid; i < 32 * 16 * 8; i += 512) hshf[i] = 0x3F80;

    // streaming weight offsets (elements): 6 per thread, one per (gate,cg)
    int woff[3][2];
    #pragma unroll
    for (int g = 0; g < 3; ++g)
        #pragma unroll
        for (int cg = 0; cg < 2; ++cg)
            woff[g][cg] = (g * DH + cbase + cg * 16 + n) * DH + kg * 8;

    // gi = (Wih . ctex^T) via SWAPPED mfma -> lane (n,kg) elem e holds gi for
    // (gatecol cbase+cg*16+kg*4+e, batchrow n). Then add per-col biases.
    const v4f vzero = {0.f, 0.f, 0.f, 0.f};
    v4f gi[3][2];
    #pragma unroll
    for (int g = 0; g < 3; ++g)
        #pragma unroll
        for (int cg = 0; cg < 2; ++cg) gi[g][cg] = vzero;

    #pragma unroll
    for (int kt = 0; kt < 4; ++kt) {
        v8s actex = *(const v8s*)&ctex[(size_t)(rb + n) * EH + kt * 32 + kg * 8];
        #pragma unroll
        for (int g = 0; g < 3; ++g)
            #pragma unroll
            for (int cg = 0; cg < 2; ++cg) {
                v8s b = *(const v8s*)
                    &wihp[(size_t)(g * DH + cbase + cg * 16 + n) * 136 + kt * 32 + kg * 8];
                gi[g][cg] = __builtin_amdgcn_mfma_f32_16x16x32_bf16(b, actex, gi[g][cg], 0, 0, 0);
            }
    }

    // biases + wy + bN -> slabs (one-time, off critical path; stride 29 odd)
    #pragma unroll
    for (int g = 0; g < 3; ++g) {
        const float sc = (g < 2) ? SC_S : SC_T;
        #pragma unroll
        for (int cg = 0; cg < 2; ++cg) {
            #pragma unroll
            for (int e = 0; e < 4; ++e) {
                const int gcol = g * DH + cbase + cg * 16 + kg * 4 + e;
                float bb = sc * (dbih[gcol] + ((g < 2) ? dbhh[gcol] : 0.f));
                gi[g][cg][e] += bb;
                wysh[tid * 29 + (g * 2 + cg) * 4 + e] = bf2f(wihp[(size_t)gcol * 136 + 128]);
            }
        }
    }
    #pragma unroll
    for (int g = 0; g < 3; ++g)
        #pragma unroll
        for (int cg = 0; cg < 2; ++cg)
            *(v4f*)&gish[tid * 29 + (g * 2 + cg) * 4] = gi[g][cg];
    #pragma unroll
    for (int e = 0; e < 4; ++e) {
        gish[tid * 29 + 24 + e] = SC_T * dbhh[2 * DH + cbase + 0 * 16 + kg * 4 + e]; // bN cg0
        wysh[tid * 29 + 24 + e] = SC_T * dbhh[2 * DH + cbase + 1 * 16 + kg * 4 + e]; // bN cg1
    }

    const float4 lb4 = *(const float4*)linb;
    float hprev[2][4];
    #pragma unroll
    for (int cg = 0; cg < 2; ++cg)
        #pragma unroll
        for (int e = 0; e < 4; ++e) hprev[cg][e] = 1.0f;

    // opaque weight base: re-materialized each t-iteration via empty asm so
    // LICM cannot hoist the 48 in-loop loads into (spilled) registers.
    unsigned long long wau = (unsigned long long)dWhh_bf;

    __syncthreads();

    for (int t = 0; t < DSTEPS; ++t) {
        asm volatile("" : "+v"(wau));
        const unsigned short* wroot = (const unsigned short*)wau;
        const float yv = ysh[n][t];

        v4f ar[2], az[2], an[2];
        #pragma unroll
        for (int cg = 0; cg < 2; ++cg) { ar[cg] = vzero; az[cg] = vzero; an[cg] = vzero; }

        #pragma unroll
        for (int kt = 0; kt < 8; ++kt) {
            v8s a = *(const v8s*)&hshf[((kt * 4 + kg) * 16 + n) * 8];
            #pragma unroll
            for (int cg = 0; cg < 2; ++cg) {
                v8s b0 = *(const v8s*)&wroot[woff[0][cg] + kt * 32];
                v8s b1 = *(const v8s*)&wroot[woff[1][cg] + kt * 32];
                v8s b2 = *(const v8s*)&wroot[woff[2][cg] + kt * 32];
                ar[cg] = __builtin_amdgcn_mfma_f32_16x16x32_bf16(b0, a, ar[cg], 0, 0, 0);
                az[cg] = __builtin_amdgcn_mfma_f32_16x16x32_bf16(b1, a, az[cg], 0, 0, 0);
                an[cg] = __builtin_amdgcn_mfma_f32_16x16x32_bf16(b2, a, an[cg], 0, 0, 0);
            }
        }
        __syncthreads();   // all reads of h_t complete

        #pragma unroll
        for (int cg = 0; cg < 2; ++cg) {
            v4f giR = *(const v4f*)&gish[tid * 29 + (0 * 2 + cg) * 4];
            v4f giZ = *(const v4f*)&gish[tid * 29 + (1 * 2 + cg) * 4];
            v4f giN = *(const v4f*)&gish[tid * 29 + (2 * 2 + cg) * 4];
            v4f wyR = *(const v4f*)&wysh[tid * 29 + (0 * 2 + cg) * 4];
            v4f wyZ = *(const v4f*)&wysh[tid * 29 + (1 * 2 + cg) * 4];
            v4f wyN = *(const v4f*)&wysh[tid * 29 + (2 * 2 + cg) * 4];
            v4f bN  = (cg == 0) ? *(const v4f*)&gish[tid * 29 + 24]
                                : *(const v4f*)&wysh[tid * 29 + 24];
            float hh[4];
            #pragma unroll
            for (int e = 0; e < 4; ++e) {
                float r  = frcp(1.f + fexp2(giR[e] + yv * wyR[e] + ar[cg][e]));
                float z  = frcp(1.f + fexp2(giZ[e] + yv * wyZ[e] + az[cg][e]));
                float nn = 1.f - 2.f * frcp(
                    fexp2(giN[e] + yv * wyN[e] + r * (an[cg][e] + bN[e])) + 1.f);
                float h  = nn + z * (hprev[cg][e] - nn);
                hprev[cg][e] = h;
                hh[e] = h;
            }
            const unsigned int p01 = cvt2bf(hh[0], hh[1]);
            const unsigned int p23 = cvt2bf(hh[2], hh[3]);
            const int base = cbase + cg * 16 + kg * 4;       // 4 consecutive cols
            const int idx = (((base >> 3) * 16) + n) * 8 + (base & 7);
            *(uint2*)&hshf[idx] = (uint2){p01, p23};         // one b64 store
        }
        __syncthreads();   // h_{t+1} visible

        if (w == (t & 7)) {   // out-proj, rotated across waves
            v4f o4 = vzero;
            #pragma unroll
            for (int kt = 0; kt < 8; ++kt) {
                v8s a = *(const v8s*)&hshf[((kt * 4 + kg) * 16 + n) * 8];
                v8s b = *(const v8s*)&lwf[((kt * 4 + kg) * 16 + n) * 8];
                o4 = __builtin_amdgcn_mfma_f32_16x16x32_bf16(b, a, o4, 0, 0, 0);
            }
            if (kg == 0) {     // lane holds out cols 0..3 for row n
                float4 ov = {o4[0] + lb4.x, o4[1] + lb4.y, o4[2] + lb4.z, o4[3] + lb4.w};
                *(float4*)&out[(size_t)(rb + n) * (S_SZ * 4) + t * 4] = ov;
            }
        }
    }

    // tail pad: out[:, 10:, :] = 1.0
    for (int j = tid; j < 16 * 512; j += 512) {
        int row = j >> 9, c = j & 511;
        if (c >= DSTEPS * 4) out[(size_t)(rb + row) * 512 + c] = 1.0f;
    }
}

// ---------------------------------------------------------------- launch
extern "C" void kernel_launch(void* const* d_in, const int* in_sizes, int n_in,
                              void* d_out, int out_size, void* d_ws, size_t ws_size,
                              hipStream_t stream)
{
    const float* x    = (const float*)d_in[0];
    const float* y    = (const float*)d_in[1];
    const float* eWih = (const float*)d_in[2];
    const float* eWhh = (const float*)d_in[3];
    const float* ebih = (const float*)d_in[4];
    const float* ebhh = (const float*)d_in[5];
    const float* dWih = (const float*)d_in[6];
    const float* dWhh = (const float*)d_in[7];
    const float* dbih = (const float*)d_in[8];
    const float* dbhh = (const float*)d_in[9];
    const float* linW = (const float*)d_in[10];
    const float* linb = (const float*)d_in[11];
    float* out = (float*)d_out;

    char* ws = (char*)d_ws;
    // ws layout (bytes):
    //   wihp     @ 0      : 768*136*2 = 208896
    //   dWhh_bf  @ 208896 : 768*256*2 = 393216  -> 602112
    //   ctex     @ 602112 : 4096*128*2 = 1048576 -> 1650688
    unsigned short* wihp    = (unsigned short*)(ws);
    unsigned short* dWhh_bf = (unsigned short*)(ws + 208896);
    unsigned short* ctex    = (unsigned short*)(ws + 602112);

    enc_kernel<<<256, 512, 0, stream>>>(x, eWih, eWhh, ebih, ebhh,
                                        dWih, dWhh, wihp, dWhh_bf, ctex);
    dec_all_kernel<<<256, 512, 0, stream>>>(dWhh_bf, wihp, dbih, dbhh, y,
                                            ctex, linW, linb, out);
}

// Round 14
// 209.217 us; speedup vs baseline: 1.3791x; 1.3791x over previous
//
#include <hip/hip_runtime.h>

#define B_SZ 4096
#define S_SZ 128
#define XD 5
#define EH 128
#define DH 256
#define DSTEPS 10

typedef short v8s __attribute__((ext_vector_type(8)));
typedef float v4f __attribute__((ext_vector_type(4)));

__device__ __forceinline__ float bf2f(unsigned short u) {
    union { unsigned int i; float f; } v; v.i = ((unsigned int)u) << 16; return v.f;
}
__device__ __forceinline__ unsigned short f2bf(float f) {
    union { float f; unsigned int i; } v; v.f = f;
    unsigned int x = v.i;
    return (unsigned short)((x + 0x7FFFu + ((x >> 16) & 1u)) >> 16);
}
__device__ __forceinline__ float fexp2(float x) { return __builtin_amdgcn_exp2f(x); }
__device__ __forceinline__ float frcp(float x) { return __builtin_amdgcn_rcpf(x); }
// pack 2 f32 -> 1 u32 of 2 bf16 (low word = first operand). HW-verified.
__device__ __forceinline__ unsigned int cvt2bf(float lo, float hi) {
    unsigned int r;
    asm("v_cvt_pk_bf16_f32 %0, %1, %2" : "=v"(r) : "v"(lo), "v"(hi));
    return r;
}

#define SC_S (-1.44269504088896f)   // sigmoid: rcp(1+exp2(SC_S*x))
#define SC_T ( 2.88539008177793f)   // tanh:    1-2*rcp(exp2(SC_T*x)+1)

// ---------------------------------------------------------------- encoder v4
// UNCHANGED from the measured-good R6/R8 version (104.5 us incl. the
// decoder weight-conversion side-job).
__global__ __launch_bounds__(512) void enc_kernel(
    const float* __restrict__ x,       // [B][S][5] fp32
    const float* __restrict__ Wih32,   // [384][5] fp32
    const float* __restrict__ Whh32,   // [384][128] fp32
    const float* __restrict__ bih,     // [384] fp32
    const float* __restrict__ bhh,     // [384] fp32
    const float* __restrict__ dWih,    // [768][129] fp32
    const float* __restrict__ dWhh,    // [768][256] fp32
    unsigned short* __restrict__ wihp,     // out: [768][136] bf16 (col128=y wt), SCALED
    unsigned short* __restrict__ dWhh_bf,  // out: [768][256] bf16, SCALED
    unsigned short* __restrict__ ctex)     // out: [B][128] bf16
{
    __shared__ unsigned short xs[S_SZ][16][8];     // 32 KB (slot5 = 1.0)
    __shared__ unsigned short hb[2][16][136];      // 8.5 KB, +8 pad
    __shared__ __align__(16) unsigned short zpad[8];

    const int tid = threadIdx.x;
    const int bid = blockIdx.x;
    const int wv = tid >> 6;
    const int lane = tid & 63;
    const int n = lane & 15;
    const int kg = lane >> 4;       // K-group / C-row quad
    const int r0 = bid * 16;

    // side-job: decoder weight conversion WITH activation scales folded in.
    for (int i = bid * 512 + tid; i < 768 * 256; i += 131072) {
        const float sc = ((i >> 8) < 512) ? SC_S : SC_T;
        dWhh_bf[i] = f2bf(sc * dWhh[i]);
    }
    for (int i = bid * 512 + tid; i < 768 * 136; i += 131072) {
        int col = i / 136, k = i - col * 136;
        const float sc = (col < 512) ? SC_S : SC_T;
        wihp[i] = (k < 129) ? f2bf(sc * dWih[col * 129 + k]) : (unsigned short)0;
    }

    for (int i = tid; i < 2 * 16 * 136; i += 512) ((unsigned short*)hb)[i] = 0;
    if (tid < 8) zpad[tid] = 0;
    for (int i = tid; i < 16 * S_SZ * 8; i += 512) {
        int m = i >> 10;
        int rem = i & 1023;
        int t = rem >> 3;
        int j = rem & 7;
        unsigned short v = 0;
        if (j < XD) v = f2bf(x[(size_t)(r0 + m) * (S_SZ * XD) + t * XD + j]);
        else if (j == XD) v = 0x3F80;          // constant-1 bias carrier
        xs[t][m][j] = v;
    }

    const int colw = wv * 16 + n;
    v8s fw[3][4];
    v8s fx[3];
    #pragma unroll
    for (int g = 0; g < 3; ++g) {
        const float sc = (g < 2) ? SC_S : SC_T;
        const int gcol = g * EH + colw;
        #pragma unroll
        for (int kt = 0; kt < 4; ++kt) {
            const float* p = &Whh32[(size_t)gcol * EH + kt * 32 + kg * 8];
            float4 lo = *(const float4*)p;
            float4 hi = *(const float4*)(p + 4);
            v8s f;
            f[0] = (short)f2bf(sc * lo.x); f[1] = (short)f2bf(sc * lo.y);
            f[2] = (short)f2bf(sc * lo.z); f[3] = (short)f2bf(sc * lo.w);
            f[4] = (short)f2bf(sc * hi.x); f[5] = (short)f2bf(sc * hi.y);
            f[6] = (short)f2bf(sc * hi.z); f[7] = (short)f2bf(sc * hi.w);
            fw[g][kt] = f;
        }
        v8s t = {0, 0, 0, 0, 0, 0, 0, 0};
        if (kg == 0) {
            const float* p = &Wih32[gcol * XD];
            #pragma unroll
            for (int j = 0; j < XD; ++j) t[j] = (short)f2bf(sc * p[j]);
            float b = (g < 2) ? (sc * (bih[gcol] + bhh[gcol]))
                              : (sc * bih[gcol]);
            t[XD] = (short)f2bf(b);
        }
        fx[g] = t;
    }
    const float bhn = SC_T * bhh[2 * EH + colw];

    const v4f vzero = {0.f, 0.f, 0.f, 0.f};
    float hst[4] = {0.f, 0.f, 0.f, 0.f};
    __syncthreads();

    #pragma unroll 2
    for (int t = 0; t < S_SZ; ++t) {
        const int p = t & 1;
        v8s a[4];
        #pragma unroll
        for (int kt = 0; kt < 4; ++kt)
            a[kt] = *(const v8s*)&hb[p][n][kt * 32 + kg * 8];
        const unsigned short* xsrc = (kg == 0) ? &xs[t][n][0] : &zpad[0];
        v8s ax = *(const v8s*)xsrc;

        v4f accr  = __builtin_amdgcn_mfma_f32_16x16x32_bf16(a[0], fw[0][0], vzero, 0, 0, 0);
        v4f accz  = __builtin_amdgcn_mfma_f32_16x16x32_bf16(a[0], fw[1][0], vzero, 0, 0, 0);
        v4f acchn = __builtin_amdgcn_mfma_f32_16x16x32_bf16(a[0], fw[2][0], vzero, 0, 0, 0);
        #pragma unroll
        for (int kt = 1; kt < 4; ++kt) {
            accr  = __builtin_amdgcn_mfma_f32_16x16x32_bf16(a[kt], fw[0][kt], accr, 0, 0, 0);
            accz  = __builtin_amdgcn_mfma_f32_16x16x32_bf16(a[kt], fw[1][kt], accz, 0, 0, 0);
            acchn = __builtin_amdgcn_mfma_f32_16x16x32_bf16(a[kt], fw[2][kt], acchn, 0, 0, 0);
        }
        accr = __builtin_amdgcn_mfma_f32_16x16x32_bf16(ax, fx[0], accr, 0, 0, 0);
        accz = __builtin_amdgcn_mfma_f32_16x16x32_bf16(ax, fx[1], accz, 0, 0, 0);
        v4f accin = __builtin_amdgcn_mfma_f32_16x16x32_bf16(ax, fx[2], vzero, 0, 0, 0);

        float hnew[4];
        #pragma unroll
        for (int e = 0; e < 4; ++e) {
            float r  = frcp(1.f + fexp2(accr[e]));
            float z  = frcp(1.f + fexp2(accz[e]));
            float nn = 1.f - 2.f * frcp(fexp2(accin[e] + r * (acchn[e] + bhn)) + 1.f);
            float h  = nn + z * (hst[e] - nn);
            hst[e] = h;
            hnew[e] = h;
        }
        const unsigned int pk01 = cvt2bf(hnew[0], hnew[1]);
        const unsigned int pk23 = cvt2bf(hnew[2], hnew[3]);
        hb[1 - p][kg * 4 + 0][colw] = (unsigned short)(pk01 & 0xFFFFu);
        hb[1 - p][kg * 4 + 1][colw] = (unsigned short)(pk01 >> 16);
        hb[1 - p][kg * 4 + 2][colw] = (unsigned short)(pk23 & 0xFFFFu);
        hb[1 - p][kg * 4 + 3][colw] = (unsigned short)(pk23 >> 16);
        __syncthreads();
    }
    #pragma unroll
    for (int e = 0; e < 4; ++e)
        ctex[(size_t)(r0 + kg * 4 + e) * EH + colw] = f2bf(hst[e]);
}

// ---------------------------------------------------------------- decoder v7
// EXACT reproduction of R10's fused dec phase (the fastest dec measured,
// ~40us) as a standalone kernel: 256 blocks x 1024 thr (16 waves, 4/SIMD
// TLP), each wave owns 16 cols of EACH gate. fB[3][8] as PLAIN loads from
// the pre-converted bf16 workspace — the compiler rematerializes them
// in-loop from L2 (R10: VGPR=64), which beats both "resident" (spills,
// R7/R9/R12) and opaque-base streaming at 8 waves (TLP-starved, R13).
// Do NOT fight that codegen. LDS 133 KB -> 1 block/CU, occupancy ~45%.
__global__ __launch_bounds__(1024)
void dec_all_kernel(
    const unsigned short* __restrict__ dWhh_bf, // [768][256] bf16, SCALED
    const unsigned short* __restrict__ wihp,    // [768][136] bf16, SCALED
    const float* __restrict__ dbih,   // [768]
    const float* __restrict__ dbhh,   // [768]
    const float* __restrict__ y,      // [B][128] fp32
    const unsigned short* __restrict__ ctex,  // [B][128] bf16
    const float* __restrict__ linW,   // [4][256] fp32
    const float* __restrict__ linb,   // [4] fp32
    float* __restrict__ out)          // [B][S][4] fp32
{
    __shared__ float gwsh[1024 * 29];              // 116 KB const slab
    __shared__ unsigned short hshf[32 * 16 * 8];   // 8 KB h state (frag)
    __shared__ unsigned short lwf[32 * 16 * 8];    // 8 KB linW (frag)
    __shared__ float ysh[16][DSTEPS];              // 640 B y slab

    const int tid = threadIdx.x;
    const int wv = tid >> 6;        // 0..15
    const int lane = tid & 63;
    const int n = lane & 15;
    const int kg = lane >> 4;
    const int rb = blockIdx.x * 16;
    const int colb = wv * 16;       // this wave's 16 cols (per gate)

    // stage linW into frag layout (first 512 threads only)
    if (tid < 512) {
        int col = tid >> 5, kgrp = tid & 31;
        unsigned short v8[8];
        #pragma unroll
        for (int j = 0; j < 8; ++j)
            v8[j] = (col < 4) ? f2bf(linW[col * 256 + kgrp * 8 + j]) : (unsigned short)0;
        *(uint4*)&lwf[(kgrp * 16 + col) * 8] = *(uint4*)v8;
    }
    // stage y slab
    if (tid < 16 * DSTEPS) {
        int row = tid / DSTEPS, tt = tid - row * DSTEPS;
        ysh[row][tt] = y[(size_t)(rb + row) * S_SZ + tt];
    }
    // h0 = 1
    for (int i = tid; i < 32 * 16 * 8; i += 1024) hshf[i] = 0x3F80;

    // Whh B-frags: plain loads, compiler free to keep or remat (R10 codegen)
    v8s fB[3][8];
    #pragma unroll
    for (int g = 0; g < 3; ++g)
        #pragma unroll
        for (int kt = 0; kt < 8; ++kt)
            fB[g][kt] = *(const v8s*)
                &dWhh_bf[(size_t)(g * DH + colb + n) * DH + kt * 32 + kg * 8];

    // gi = (Wih . ctex^T) via swapped mfma: lane (n,kg) elem e ->
    // (gatecol colb+kg*4+e, batchrow n)
    const v4f vzero = {0.f, 0.f, 0.f, 0.f};
    v4f gi[3];
    #pragma unroll
    for (int g = 0; g < 3; ++g) gi[g] = vzero;

    #pragma unroll
    for (int kt = 0; kt < 4; ++kt) {
        v8s actex = *(const v8s*)&ctex[(size_t)(rb + n) * EH + kt * 32 + kg * 8];
        #pragma unroll
        for (int g = 0; g < 3; ++g) {
            v8s bw = *(const v8s*)
                &wihp[(size_t)(g * DH + colb + n) * 136 + kt * 32 + kg * 8];
            gi[g] = __builtin_amdgcn_mfma_f32_16x16x32_bf16(bw, actex, gi[g], 0, 0, 0);
        }
    }

    // slab layout per thread (stride 29): [0..11] gi, [12..23] wy, [24..27] bN
    #pragma unroll
    for (int g = 0; g < 3; ++g) {
        const float sc = (g < 2) ? SC_S : SC_T;
        #pragma unroll
        for (int e = 0; e < 4; ++e) {
            const int gcol = g * DH + colb + kg * 4 + e;
            gi[g][e] += sc * (dbih[gcol] + ((g < 2) ? dbhh[gcol] : 0.f));
            gwsh[tid * 29 + 12 + g * 4 + e] = bf2f(wihp[(size_t)gcol * 136 + 128]);
        }
        *(v4f*)&gwsh[tid * 29 + g * 4] = gi[g];
    }
    #pragma unroll
    for (int e = 0; e < 4; ++e)
        gwsh[tid * 29 + 24 + e] = SC_T * dbhh[2 * DH + colb + kg * 4 + e];

    float hprev[4] = {1.f, 1.f, 1.f, 1.f};
    __syncthreads();

    for (int t = 0; t < DSTEPS; ++t) {
        const float yv = ysh[n][t];

        v4f ar = vzero, az = vzero, an = vzero;
        #pragma unroll
        for (int kt = 0; kt < 8; ++kt) {
            v8s a = *(const v8s*)&hshf[((kt * 4 + kg) * 16 + n) * 8];
            ar = __builtin_amdgcn_mfma_f32_16x16x32_bf16(fB[0][kt], a, ar, 0, 0, 0);
            az = __builtin_amdgcn_mfma_f32_16x16x32_bf16(fB[1][kt], a, az, 0, 0, 0);
            an = __builtin_amdgcn_mfma_f32_16x16x32_bf16(fB[2][kt], a, an, 0, 0, 0);
        }
        __syncthreads();   // all reads of h_t complete

        float hh[4];
        #pragma unroll
        for (int e = 0; e < 4; ++e) {
            const float giR = gwsh[tid * 29 + 0 + e];
            const float giZ = gwsh[tid * 29 + 4 + e];
            const float giN = gwsh[tid * 29 + 8 + e];
            const float wyR = gwsh[tid * 29 + 12 + e];
            const float wyZ = gwsh[tid * 29 + 16 + e];
            const float wyN = gwsh[tid * 29 + 20 + e];
            const float bN  = gwsh[tid * 29 + 24 + e];
            float r  = frcp(1.f + fexp2(giR + yv * wyR + ar[e]));
            float z  = frcp(1.f + fexp2(giZ + yv * wyZ + az[e]));
            float nn = 1.f - 2.f * frcp(
                fexp2(giN + yv * wyN + r * (an[e] + bN)) + 1.f);
            float h  = nn + z * (hprev[e] - nn);
            hprev[e] = h;
            hh[e] = h;
        }
        const unsigned int p01 = cvt2bf(hh[0], hh[1]);
        const unsigned int p23 = cvt2bf(hh[2], hh[3]);
        const int base = colb + kg * 4;        // 4 consecutive cols
        const int idx = (((base >> 3) * 16) + n) * 8 + (base & 7);
        *(uint2*)&hshf[idx] = (uint2){p01, p23};
        __syncthreads();   // h_{t+1} visible

        if (wv == t) {     // out-proj, rotated across waves (t<10<16)
            v4f o4 = vzero;
            #pragma unroll
            for (int kt = 0; kt < 8; ++kt) {
                v8s a = *(const v8s*)&hshf[((kt * 4 + kg) * 16 + n) * 8];
                v8s b = *(const v8s*)&lwf[((kt * 4 + kg) * 16 + n) * 8];
                o4 = __builtin_amdgcn_mfma_f32_16x16x32_bf16(b, a, o4, 0, 0, 0);
            }
            if (kg == 0) {
                const float4 lb4 = *(const float4*)linb;
                float4 ov = {o4[0] + lb4.x, o4[1] + lb4.y, o4[2] + lb4.z, o4[3] + lb4.w};
                *(float4*)&out[(size_t)(rb + n) * (S_SZ * 4) + t * 4] = ov;
            }
        }
    }

    // tail pad: out[:, 10:, :] = 1.0
    for (int j = tid; j < 16 * 512; j += 1024) {
        int row = j >> 9, c = j & 511;
        if (c >= DSTEPS * 4) out[(size_t)(rb + row) * 512 + c] = 1.0f;
    }
}

// ---------------------------------------------------------------- launch
extern "C" void kernel_launch(void* const* d_in, const int* in_sizes, int n_in,
                              void* d_out, int out_size, void* d_ws, size_t ws_size,
                              hipStream_t stream)
{
    const float* x    = (const float*)d_in[0];
    const float* y    = (const float*)d_in[1];
    const float* eWih = (const float*)d_in[2];
    const float* eWhh = (const float*)d_in[3];
    const float* ebih = (const float*)d_in[4];
    const float* ebhh = (const float*)d_in[5];
    const float* dWih = (const float*)d_in[6];
    const float* dWhh = (const float*)d_in[7];
    const float* dbih = (const float*)d_in[8];
    const float* dbhh = (const float*)d_in[9];
    const float* linW = (const float*)d_in[10];
    const float* linb = (const float*)d_in[11];
    float* out = (float*)d_out;

    char* ws = (char*)d_ws;
    // ws layout (bytes):
    //   wihp     @ 0      : 768*136*2 = 208896
    //   dWhh_bf  @ 208896 : 768*256*2 = 393216  -> 602112
    //   ctex     @ 602112 : 4096*128*2 = 1048576 -> 1650688
    unsigned short* wihp    = (unsigned short*)(ws);
    unsigned short* dWhh_bf = (unsigned short*)(ws + 208896);
    unsigned short* ctex    = (unsigned short*)(ws + 602112);

    enc_kernel<<<256, 512, 0, stream>>>(x, eWih, eWhh, ebih, ebhh,
                                        dWih, dWhh, wihp, dWhh_bf, ctex);
    dec_all_kernel<<<256, 1024, 0, stream>>>(dWhh_bf, wihp, dbih, dbhh, y,
                                             ctex, linW, linb, out);
}

// Round 15
// 202.004 us; speedup vs baseline: 1.4283x; 1.0357x over previous
//
#include <hip/hip_runtime.h>

#define B_SZ 4096
#define S_SZ 128
#define XD 5
#define EH 128
#define DH 256
#define DSTEPS 10

typedef short v8s __attribute__((ext_vector_type(8)));
typedef float v4f __attribute__((ext_vector_type(4)));

__device__ __forceinline__ float bf2f(unsigned short u) {
    union { unsigned int i; float f; } v; v.i = ((unsigned int)u) << 16; return v.f;
}
__device__ __forceinline__ unsigned short f2bf(float f) {
    union { float f; unsigned int i; } v; v.f = f;
    unsigned int x = v.i;
    return (unsigned short)((x + 0x7FFFu + ((x >> 16) & 1u)) >> 16);
}
__device__ __forceinline__ float fexp2(float x) { return __builtin_amdgcn_exp2f(x); }
__device__ __forceinline__ float frcp(float x) { return __builtin_amdgcn_rcpf(x); }
// pack 2 f32 -> 1 u32 of 2 bf16 (low word = first operand). HW-verified.
__device__ __forceinline__ unsigned int cvt2bf(float lo, float hi) {
    unsigned int r;
    asm("v_cvt_pk_bf16_f32 %0, %1, %2" : "=v"(r) : "v"(lo), "v"(hi));
    return r;
}

#define SC_S (-1.44269504088896f)   // sigmoid: rcp(1+exp2(SC_S*x))
#define SC_T ( 2.88539008177793f)   // tanh:    1-2*rcp(exp2(SC_T*x)+1)

// ---------------------------------------------------------------- encoder v5
// enc v4 (measured 103us) + SWAPPED MFMA operands: mfma(W, h) instead of
// mfma(h, W). A/B frag lane-maps are identical on gfx950 (verified by dec
// v5, R7/R8 PASS) so all register loading is unchanged; C transposes so
// lane (n,kg) owns batch-row n x 4 CONSECUTIVE h-cols (wv*16+kg*4+e).
// Gains: h-write 4x ds_write_b16 -> 1x ds_write_b64 (2-way bank = free);
// ctex epilogue -> single packed uint2. Slot-5 bias carrier still lands
// per-column bias (bias rides A-row = gate col); bhn becomes a 4-vector.
__global__ __launch_bounds__(512) void enc_kernel(
    const float* __restrict__ x,       // [B][S][5] fp32
    const float* __restrict__ Wih32,   // [384][5] fp32
    const float* __restrict__ Whh32,   // [384][128] fp32
    const float* __restrict__ bih,     // [384] fp32
    const float* __restrict__ bhh,     // [384] fp32
    const float* __restrict__ dWih,    // [768][129] fp32
    const float* __restrict__ dWhh,    // [768][256] fp32
    unsigned short* __restrict__ wihp,     // out: [768][136] bf16 (col128=y wt), SCALED
    unsigned short* __restrict__ dWhh_bf,  // out: [768][256] bf16, SCALED
    unsigned short* __restrict__ ctex)     // out: [B][128] bf16
{
    __shared__ unsigned short xs[S_SZ][16][8];     // 32 KB (slot5 = 1.0)
    __shared__ unsigned short hb[2][16][136];      // 8.5 KB, +8 pad
    __shared__ __align__(16) unsigned short zpad[8];

    const int tid = threadIdx.x;
    const int bid = blockIdx.x;
    const int wv = tid >> 6;
    const int lane = tid & 63;
    const int n = lane & 15;
    const int kg = lane >> 4;       // K-group / C-row quad
    const int r0 = bid * 16;

    // side-job: decoder weight conversion WITH activation scales folded in.
    for (int i = bid * 512 + tid; i < 768 * 256; i += 131072) {
        const float sc = ((i >> 8) < 512) ? SC_S : SC_T;
        dWhh_bf[i] = f2bf(sc * dWhh[i]);
    }
    for (int i = bid * 512 + tid; i < 768 * 136; i += 131072) {
        int col = i / 136, k = i - col * 136;
        const float sc = (col < 512) ? SC_S : SC_T;
        wihp[i] = (k < 129) ? f2bf(sc * dWih[col * 129 + k]) : (unsigned short)0;
    }

    for (int i = tid; i < 2 * 16 * 136; i += 512) ((unsigned short*)hb)[i] = 0;
    if (tid < 8) zpad[tid] = 0;
    for (int i = tid; i < 16 * S_SZ * 8; i += 512) {
        int m = i >> 10;
        int rem = i & 1023;
        int t = rem >> 3;
        int j = rem & 7;
        unsigned short v = 0;
        if (j < XD) v = f2bf(x[(size_t)(r0 + m) * (S_SZ * XD) + t * XD + j]);
        else if (j == XD) v = 0x3F80;          // constant-1 bias carrier
        xs[t][m][j] = v;
    }

    const int colw = wv * 16 + n;              // weight col held by this lane
    v8s fw[3][4];
    v8s fx[3];
    #pragma unroll
    for (int g = 0; g < 3; ++g) {
        const float sc = (g < 2) ? SC_S : SC_T;
        const int gcol = g * EH + colw;
        #pragma unroll
        for (int kt = 0; kt < 4; ++kt) {
            const float* p = &Whh32[(size_t)gcol * EH + kt * 32 + kg * 8];
            float4 lo = *(const float4*)p;
            float4 hi = *(const float4*)(p + 4);
            v8s f;
            f[0] = (short)f2bf(sc * lo.x); f[1] = (short)f2bf(sc * lo.y);
            f[2] = (short)f2bf(sc * lo.z); f[3] = (short)f2bf(sc * lo.w);
            f[4] = (short)f2bf(sc * hi.x); f[5] = (short)f2bf(sc * hi.y);
            f[6] = (short)f2bf(sc * hi.z); f[7] = (short)f2bf(sc * hi.w);
            fw[g][kt] = f;
        }
        v8s t = {0, 0, 0, 0, 0, 0, 0, 0};
        if (kg == 0) {
            const float* p = &Wih32[gcol * XD];
            #pragma unroll
            for (int j = 0; j < XD; ++j) t[j] = (short)f2bf(sc * p[j]);
            float b = (g < 2) ? (sc * (bih[gcol] + bhh[gcol]))
                              : (sc * bih[gcol]);
            t[XD] = (short)f2bf(b);
        }
        fx[g] = t;
    }
    // n-gate hidden-side bias for this lane's 4 OUTPUT cols (swapped layout)
    float bhn4[4];
    #pragma unroll
    for (int e = 0; e < 4; ++e)
        bhn4[e] = SC_T * bhh[2 * EH + wv * 16 + kg * 4 + e];

    const v4f vzero = {0.f, 0.f, 0.f, 0.f};
    float hst[4] = {0.f, 0.f, 0.f, 0.f};
    __syncthreads();

    #pragma unroll 2
    for (int t = 0; t < S_SZ; ++t) {
        const int p = t & 1;
        v8s a[4];
        #pragma unroll
        for (int kt = 0; kt < 4; ++kt)
            a[kt] = *(const v8s*)&hb[p][n][kt * 32 + kg * 8];
        const unsigned short* xsrc = (kg == 0) ? &xs[t][n][0] : &zpad[0];
        v8s ax = *(const v8s*)xsrc;

        // SWAPPED: A = weights, B = h/x. C: lane (n,kg) elem e =
        // (gatecol wv*16+kg*4+e, batchrow n).
        v4f accr  = __builtin_amdgcn_mfma_f32_16x16x32_bf16(fw[0][0], a[0], vzero, 0, 0, 0);
        v4f accz  = __builtin_amdgcn_mfma_f32_16x16x32_bf16(fw[1][0], a[0], vzero, 0, 0, 0);
        v4f acchn = __builtin_amdgcn_mfma_f32_16x16x32_bf16(fw[2][0], a[0], vzero, 0, 0, 0);
        #pragma unroll
        for (int kt = 1; kt < 4; ++kt) {
            accr  = __builtin_amdgcn_mfma_f32_16x16x32_bf16(fw[0][kt], a[kt], accr, 0, 0, 0);
            accz  = __builtin_amdgcn_mfma_f32_16x16x32_bf16(fw[1][kt], a[kt], accz, 0, 0, 0);
            acchn = __builtin_amdgcn_mfma_f32_16x16x32_bf16(fw[2][kt], a[kt], acchn, 0, 0, 0);
        }
        accr = __builtin_amdgcn_mfma_f32_16x16x32_bf16(fx[0], ax, accr, 0, 0, 0);
        accz = __builtin_amdgcn_mfma_f32_16x16x32_bf16(fx[1], ax, accz, 0, 0, 0);
        v4f accin = __builtin_amdgcn_mfma_f32_16x16x32_bf16(fx[2], ax, vzero, 0, 0, 0);

        float hnew[4];
        #pragma unroll
        for (int e = 0; e < 4; ++e) {
            float r  = frcp(1.f + fexp2(accr[e]));
            float z  = frcp(1.f + fexp2(accz[e]));
            float nn = 1.f - 2.f * frcp(fexp2(accin[e] + r * (acchn[e] + bhn4[e])) + 1.f);
            float h  = nn + z * (hst[e] - nn);
            hst[e] = h;
            hnew[e] = h;
        }
        const unsigned int pk01 = cvt2bf(hnew[0], hnew[1]);
        const unsigned int pk23 = cvt2bf(hnew[2], hnew[3]);
        // row n, 4 consecutive cols -> single b64 store (2-way bank = free)
        *(uint2*)&hb[1 - p][n][wv * 16 + kg * 4] = (uint2){pk01, pk23};
        __syncthreads();
    }
    {
        const unsigned int pk01 = cvt2bf(hst[0], hst[1]);
        const unsigned int pk23 = cvt2bf(hst[2], hst[3]);
        *(uint2*)&ctex[(size_t)(r0 + n) * EH + wv * 16 + kg * 4] = (uint2){pk01, pk23};
    }
}

// ---------------------------------------------------------------- fused decoder v3
// VERBATIM the R6-measured champion (dec in-bench ~44us; total 203.2).
// 8 waves, r/z Whh "resident" (whatever codegen results, it measured best),
// n-gate Whh in LDS (pad 258: kg phases {0,8,16,24} mod 32 banks), y slab
// in LDS, scales pre-folded by enc's side-job.
__global__ __launch_bounds__(512)
__attribute__((amdgpu_waves_per_eu(2, 2)))
void dec_all_kernel(
    const unsigned short* __restrict__ dWhh_bf, // [768][256] bf16, SCALED
    const unsigned short* __restrict__ wihp,    // [768][136] bf16, SCALED
    const float* __restrict__ dbih,   // [768]
    const float* __restrict__ dbhh,   // [768]
    const float* __restrict__ y,      // [B][128] fp32
    const unsigned short* __restrict__ ctex,  // [B][128] bf16
    const float* __restrict__ linW,   // [4][256] fp32
    const float* __restrict__ linb,   // [4] fp32
    float* __restrict__ out)          // [B][S][4] fp32
{
    __shared__ unsigned short wshn[32 * 258 * 8];  // 129 KB n-gate Whh (frag, pad 258)
    __shared__ unsigned short hshf[32 * 16 * 8];   // 8 KB   h state (frag)
    __shared__ unsigned short lwf[32 * 16 * 8];    // 8 KB   linW (frag, 4->16 pad)
    __shared__ float ysh[16][DSTEPS];              // 640 B  y slab

    const int tid  = threadIdx.x;
    const int w    = tid >> 6;
    const int lane = tid & 63;
    const int n    = lane & 15;
    const int kg   = lane >> 4;
    const int rb   = blockIdx.x * 16;
    const int cbase = w * 32;

    // stage n-gate Whh (once; coalesced global reads)
    for (int i = tid; i < 256 * 32; i += 512) {
        int col = i >> 5, kgrp = i & 31;
        uint4 v = *(const uint4*)&dWhh_bf[(size_t)(512 + col) * 256 + kgrp * 8];
        *(uint4*)&wshn[(kgrp * 258 + col) * 8] = v;
    }
    // stage linW into frag layout
    {
        int col = tid >> 5, kgrp = tid & 31;
        unsigned short v8[8];
        #pragma unroll
        for (int j = 0; j < 8; ++j)
            v8[j] = (col < 4) ? f2bf(linW[col * 256 + kgrp * 8 + j]) : (unsigned short)0;
        *(uint4*)&lwf[(kgrp * 16 + col) * 8] = *(uint4*)v8;
    }
    // stage y slab: 16 rows x 10 steps
    if (tid < 16 * DSTEPS) {
        int row = tid / DSTEPS, tt = tid - row * DSTEPS;
        ysh[row][tt] = y[(size_t)(rb + row) * S_SZ + tt];
    }
    // h0 = 1
    for (int i = tid; i < 32 * 16 * 8; i += 512) hshf[i] = 0x3F80;

    // resident r/z B-frags: 2 gates x 2 colgroups x 8 K-tiles = 128 VGPRs
    v8s fB[2][2][8];
    #pragma unroll
    for (int g = 0; g < 2; ++g)
        #pragma unroll
        for (int cg = 0; cg < 2; ++cg)
            #pragma unroll
            for (int kt = 0; kt < 8; ++kt)
                fB[g][cg][kt] = *(const v8s*)
                    &dWhh_bf[(size_t)(g * DH + cbase + cg * 16 + n) * DH + kt * 32 + kg * 8];

    // gi = ctex @ dWih[:, :128]^T + biases (all pre-scaled); y weight per col
    v4f gi[3][2];
    float wy[3][2], bNh[2];
    #pragma unroll
    for (int g = 0; g < 3; ++g)
        #pragma unroll
        for (int cg = 0; cg < 2; ++cg) {
            int gcol = g * DH + cbase + cg * 16 + n;
            const float sc = (g < 2) ? SC_S : SC_T;
            float bb = sc * (dbih[gcol] + ((g < 2) ? dbhh[gcol] : 0.f));
            gi[g][cg] = (v4f){bb, bb, bb, bb};
            wy[g][cg] = bf2f(wihp[(size_t)gcol * 136 + 128]);   // already scaled
        }
    #pragma unroll
    for (int cg = 0; cg < 2; ++cg)
        bNh[cg] = SC_T * dbhh[2 * DH + cbase + cg * 16 + n];

    #pragma unroll
    for (int kt = 0; kt < 4; ++kt) {
        v8s a = *(const v8s*)&ctex[(size_t)(rb + n) * EH + kt * 32 + kg * 8];
        #pragma unroll
        for (int g = 0; g < 3; ++g)
            #pragma unroll
            for (int cg = 0; cg < 2; ++cg) {
                v8s b = *(const v8s*)
                    &wihp[(size_t)(g * DH + cbase + cg * 16 + n) * 136 + kt * 32 + kg * 8];
                gi[g][cg] = __builtin_amdgcn_mfma_f32_16x16x32_bf16(a, b, gi[g][cg], 0, 0, 0);
            }
    }

    const float lb = (n < 4) ? linb[n] : 0.f;
    float hprev[2][4];
    #pragma unroll
    for (int cg = 0; cg < 2; ++cg)
        #pragma unroll
        for (int e = 0; e < 4; ++e) hprev[cg][e] = 1.0f;

    __syncthreads();

    for (int t = 0; t < DSTEPS; ++t) {
        float yv[4];
        #pragma unroll
        for (int e = 0; e < 4; ++e)
            yv[e] = ysh[kg * 4 + e][t];

        v4f ar[2], az[2], an[2];
        #pragma unroll
        for (int cg = 0; cg < 2; ++cg) {
            ar[cg] = (v4f){0.f, 0.f, 0.f, 0.f};
            az[cg] = (v4f){0.f, 0.f, 0.f, 0.f};
            an[cg] = (v4f){bNh[cg], bNh[cg], bNh[cg], bNh[cg]};
        }
        #pragma unroll
        for (int kt = 0; kt < 8; ++kt) {
            v8s a = *(const v8s*)&hshf[((kt * 4 + kg) * 16 + n) * 8];
            #pragma unroll
            for (int cg = 0; cg < 2; ++cg) {
                v8s bn_ = *(const v8s*)&wshn[((kt * 4 + kg) * 258 + cbase + cg * 16 + n) * 8];
                ar[cg] = __builtin_amdgcn_mfma_f32_16x16x32_bf16(a, fB[0][cg][kt], ar[cg], 0, 0, 0);
                az[cg] = __builtin_amdgcn_mfma_f32_16x16x32_bf16(a, fB[1][cg][kt], az[cg], 0, 0, 0);
                an[cg] = __builtin_amdgcn_mfma_f32_16x16x32_bf16(a, bn_,           an[cg], 0, 0, 0);
            }
        }
        __syncthreads();   // all reads of h_t complete

        #pragma unroll
        for (int cg = 0; cg < 2; ++cg) {
            const int chi = 4 * w + 2 * cg + (n >> 3);   // (col>>3)
            #pragma unroll
            for (int e = 0; e < 4; ++e) {
                float r  = frcp(1.f + fexp2(gi[0][cg][e] + yv[e] * wy[0][cg] + ar[cg][e]));
                float z  = frcp(1.f + fexp2(gi[1][cg][e] + yv[e] * wy[1][cg] + az[cg][e]));
                float nn = 1.f - 2.f * frcp(
                    fexp2(gi[2][cg][e] + yv[e] * wy[2][cg] + r * an[cg][e]) + 1.f);
                float h  = nn + z * (hprev[cg][e] - nn);
                hprev[cg][e] = h;
                hshf[(chi * 16 + kg * 4 + e) * 8 + (n & 7)] = f2bf(h);
            }
        }
        __syncthreads();   // h_{t+1} visible

        if (w == 0) {      // out-proj (overlaps other waves' next MFMA phase)
            v4f o4 = {0.f, 0.f, 0.f, 0.f};
            #pragma unroll
            for (int kt = 0; kt < 8; ++kt) {
                v8s a = *(const v8s*)&hshf[((kt * 4 + kg) * 16 + n) * 8];
                v8s b = *(const v8s*)&lwf[((kt * 4 + kg) * 16 + n) * 8];
                o4 = __builtin_amdgcn_mfma_f32_16x16x32_bf16(a, b, o4, 0, 0, 0);
            }
            if (n < 4) {
                #pragma unroll
                for (int e = 0; e < 4; ++e)
                    out[(size_t)(rb + kg * 4 + e) * (S_SZ * 4) + t * 4 + n] = o4[e] + lb;
            }
        }
    }

    // tail pad: out[:, 10:, :] = 1.0
    for (int j = tid; j < 16 * 512; j += 512) {
        int row = j >> 9, c = j & 511;
        if (c >= DSTEPS * 4) out[(size_t)(rb + row) * 512 + c] = 1.0f;
    }
}

// ---------------------------------------------------------------- launch
extern "C" void kernel_launch(void* const* d_in, const int* in_sizes, int n_in,
                              void* d_out, int out_size, void* d_ws, size_t ws_size,
                              hipStream_t stream)
{
    const float* x    = (const float*)d_in[0];
    const float* y    = (const float*)d_in[1];
    const float* eWih = (const float*)d_in[2];
    const float* eWhh = (const float*)d_in[3];
    const float* ebih = (const float*)d_in[4];
    const float* ebhh = (const float*)d_in[5];
    const float* dWih = (const float*)d_in[6];
    const float* dWhh = (const float*)d_in[7];
    const float* dbih = (const float*)d_in[8];
    const float* dbhh = (const float*)d_in[9];
    const float* linW = (const float*)d_in[10];
    const float* linb = (const float*)d_in[11];
    float* out = (float*)d_out;

    char* ws = (char*)d_ws;
    // ws layout (bytes):
    //   wihp     @ 0      : 768*136*2 = 208896
    //   dWhh_bf  @ 208896 : 768*256*2 = 393216  -> 602112
    //   ctex     @ 602112 : 4096*128*2 = 1048576 -> 1650688
    unsigned short* wihp    = (unsigned short*)(ws);
    unsigned short* dWhh_bf = (unsigned short*)(ws + 208896);
    unsigned short* ctex    = (unsigned short*)(ws + 602112);

    enc_kernel<<<256, 512, 0, stream>>>(x, eWih, eWhh, ebih, ebhh,
                                        dWih, dWhh, wihp, dWhh_bf, ctex);
    dec_all_kernel<<<256, 512, 0, stream>>>(dWhh_bf, wihp, dbih, dbhh, y,
                                            ctex, linW, linb, out);
}